// Round 9
// baseline (238.272 us; speedup 1.0000x reference)
//
#include <hip/hip_runtime.h>
#include <math.h>

#define Bn 8
#define Hd 128
#define Ld 8192
#define Pd 256
#define LC 32
#define LH 16   // half-chunk tile along l
#define NC 256  // Ld / LC

typedef __attribute__((ext_vector_type(8))) short bf16x8;
typedef __attribute__((ext_vector_type(4))) float f32x4;
#define MFMA16(a, b, c) __builtin_amdgcn_mfma_f32_16x16x32_bf16(a, b, c, 0, 0, 0)

__device__ __forceinline__ unsigned short f2bf(float f) {
  unsigned u = __float_as_uint(f);
  u = u + 0x7fffu + ((u >> 16) & 1u);  // round-to-nearest-even
  return (unsigned short)(u >> 16);
}

#if __has_builtin(__builtin_amdgcn_cvt_pk_bf16_f32)
typedef __attribute__((ext_vector_type(2))) __bf16 v2bf_t;
__device__ __forceinline__ unsigned pack2(float a, float b) {
  v2bf_t r = __builtin_amdgcn_cvt_pk_bf16_f32(a, b);  // low = a, high = b
  unsigned u;
  __builtin_memcpy(&u, &r, 4);
  return u;
}
#else
__device__ __forceinline__ unsigned pack2(float a, float b) {
  return (unsigned)f2bf(a) | ((unsigned)f2bf(b) << 16);
}
#endif

__device__ __forceinline__ float bflo(unsigned v) { return __uint_as_float(v << 16); }
__device__ __forceinline__ float bfhi(unsigned v) { return __uint_as_float(v & 0xffff0000u); }

// xs-layout slot for (p, j): word index j*256 + ((p>>2)^(j&7))*4 + (p&3).
// b128 C-frag stores: 8 words/bank (conflict-free min); per-p scan: 2-way (free).
__device__ __forceinline__ int xs_idx(int p, int j) {
  return j * 256 + ((((p >> 2) ^ (j & 7)) << 2) | (p & 3));
}

// ---------------- kernel 0: repack B,C,D into MFMA A-fragment order ----------------
__global__ void k_prep(const float* __restrict__ Bre, const float* __restrict__ Bim,
                       const float* __restrict__ Cre, const float* __restrict__ Cim,
                       const float* __restrict__ Dm,
                       bf16x8* __restrict__ Bfr, bf16x8* __restrict__ Bfi,
                       bf16x8* __restrict__ Cf, bf16x8* __restrict__ Df) {
  int tid = blockIdx.x * 256 + threadIdx.x;
  int lane = tid & 63, slot = tid >> 6;
  int q = lane >> 4, ln = lane & 15;
  if (slot < 64) {  // B tables
    int ks = slot >> 4, mt = slot & 15;
    int p = mt * 16 + ln;
    bf16x8 vr, vi;
#pragma unroll
    for (int e = 0; e < 8; ++e) {
      int h = ks * 32 + q * 8 + e;
      vr[e] = (short)f2bf(Bre[p * Hd + h]);
      vi[e] = (short)f2bf(Bim[p * Hd + h]);
    }
    Bfr[slot * 64 + lane] = vr;
    Bfi[slot * 64 + lane] = vi;
  } else if (slot < 64 + 128) {  // C table, K' = 512 interleaved (re, -im)
    int s2 = slot - 64;
    int ks = s2 >> 3, mt = s2 & 7;
    int o = mt * 16 + ln;
    bf16x8 v;
#pragma unroll
    for (int e = 0; e < 8; ++e) {
      int kp = ks * 32 + q * 8 + e;
      int p = kp >> 1;
      float val = (kp & 1) ? -Cim[o * Pd + p] : Cre[o * Pd + p];
      v[e] = (short)f2bf(val);
    }
    Cf[s2 * 64 + lane] = v;
  } else if (slot < 64 + 128 + 32) {  // D table
    int s3 = slot - 192;
    int ks = s3 >> 3, mt = s3 & 7;
    int o = mt * 16 + ln;
    bf16x8 v;
#pragma unroll
    for (int e = 0; e < 8; ++e) {
      int h = ks * 32 + q * 8 + e;
      v[e] = (short)f2bf(Dm[o * Hd + h]);
    }
    Df[s3 * 64 + lane] = v;
  }
}

// ---- u staging, 16-l half-tile: 16 rows (j) x 128 bf16 (h), 256 B/row ----
// thread t: h-pair (h2, h2+1) with h2 = 2*(t>>2); j-quad j0 = 4*(t&3).
// 4 consecutive lanes read 64B contiguous per row. XOR-swizzled 16B granules;
// LDS write banks: 2-way max (free).
__device__ __forceinline__ void stage_u16(const float* __restrict__ ub,
                                          unsigned* us32, int t) {
  int h2 = (t >> 2) * 2;
  int j0 = (t & 3) * 4;
  const float* r0 = ub + (size_t)h2 * Ld + j0;
  float4 a0 = *(const float4*)r0;
  float4 a1 = *(const float4*)(r0 + Ld);
  float ta0[4] = {a0.x, a0.y, a0.z, a0.w};
  float ta1[4] = {a1.x, a1.y, a1.z, a1.w};
#pragma unroll
  for (int i = 0; i < 4; ++i) {
    int j = j0 + i;
    int g = (h2 >> 3) ^ (j & 7);
    us32[(j * 256 + (g << 4) + ((2 * h2) & 15)) >> 2] = pack2(ta0[i], ta1[i]);
  }
}

// Bu (16 cols) = B_bar @ u_half via MFMA; stores packed bf16 (re,im) directly
// in the xs layout via b128. Wave w covers p in [64w,64w+64) -> same-wave capture.
__device__ __forceinline__ void compute_bu16(const unsigned* us32,
                                             const bf16x8* __restrict__ Bfr,
                                             const bf16x8* __restrict__ Bfi,
                                             unsigned* xs32, int t) {
  int lane = t & 63, w = t >> 6, q = lane >> 4, ln = lane & 15;
  f32x4 zz = {0.f, 0.f, 0.f, 0.f};
  f32x4 aR[4] = {zz, zz, zz, zz}, aI[4] = {zz, zz, zz, zz};
#pragma unroll
  for (int ks = 0; ks < 4; ++ks) {
    int g = (4 * ks + q) ^ (ln & 7);
    bf16x8 ubf = *(const bf16x8*)((const char*)us32 + ln * 256 + g * 16);
#pragma unroll
    for (int mt = 0; mt < 4; ++mt) {
      int tI = ks * 16 + w * 4 + mt;
      aR[mt] = MFMA16(Bfr[tI * 64 + lane], ubf, aR[mt]);
      aI[mt] = MFMA16(Bfi[tI * 64 + lane], ubf, aI[mt]);
    }
  }
#pragma unroll
  for (int mt = 0; mt < 4; ++mt) {
    int p0 = w * 64 + mt * 16 + q * 4;
    int g = (p0 >> 2) ^ (ln & 7);
    uint4 wv = make_uint4(pack2(aR[mt][0], aI[mt][0]), pack2(aR[mt][1], aI[mt][1]),
                          pack2(aR[mt][2], aI[mt][2]), pack2(aR[mt][3], aI[mt][3]));
    *(uint4*)(xs32 + ln * 256 + g * 4) = wv;  // 16B-aligned b128
  }
}

// ---------------- kernel 1: per-chunk state contribution E ----------------
// 20 KB LDS -> up to 8 blocks/CU. Two 16-l halves, scan state carried in regs.
__global__ __launch_bounds__(256, 6) void k_chunk(
    const float* __restrict__ u, const float* __restrict__ lre,
    const float* __restrict__ lim, const bf16x8* __restrict__ Bfr,
    const bf16x8* __restrict__ Bfi, float2* __restrict__ E) {
  int bc = blockIdx.x;
  int b = bc >> 8, c = bc & 255;
  __shared__ __align__(16) unsigned char smem[4096 + 16384];
  unsigned* us32 = (unsigned*)smem;
  unsigned* xs32 = (unsigned*)(smem + 4096);
  int t = threadIdx.x;
  int p = t;
  float ax = lre[p], ay = lim[p];
  const float* ub = u + (size_t)b * Hd * Ld + c * LC;
  float xr = 0.f, xi = 0.f;
#pragma unroll
  for (int hf = 0; hf < 2; ++hf) {
    if (hf) __syncthreads();  // prior cross-wave us reads done before restage
    stage_u16(ub + hf * LH, us32, t);
    __syncthreads();
    compute_bu16(us32, Bfr, Bfi, xs32, t);
    // same-wave capture + running zero-seeded total (no barrier)
#pragma unroll
    for (int j = 0; j < LH; ++j) {
      unsigned v = xs32[xs_idx(p, j)];
      float sr = xr + bflo(v), si = xi + bfhi(v);
      xr = ax * sr - ay * si;
      xi = ax * si + ay * sr;
    }
  }
  E[(size_t)bc * Pd + p] = make_float2(xr, xi);
}

// ---------------- kernel 2: parallel prefix scan over chunks ----------------
__global__ __launch_bounds__(256) void k_scan(const float* __restrict__ lre,
                                              const float* __restrict__ lim,
                                              float2* __restrict__ E) {
  __shared__ float2 arr[32][8];
  int nb = blockIdx.x;  // 0..255
  int t = threadIdx.x;
  int pl = t & 7, rq = t >> 3;  // rq = run index 0..31
  int b = nb >> 5;
  int p = ((nb & 31) << 3) + pl;
  float ax = lre[p], ay = lim[p];
  float mx = ax, my = ay;
#pragma unroll
  for (int k = 0; k < 5; ++k) {  // m = a^32
    float nx = mx * mx - my * my, ny = 2.f * mx * my;
    mx = nx; my = ny;
  }
  size_t base = ((size_t)(b * NC + rq * 8)) * Pd + p;
  float2 pre[8];
  float cr = 0.f, ci = 0.f;
#pragma unroll
  for (int i = 0; i < 8; ++i) {
    float2 e = E[base + (size_t)i * Pd];
    pre[i] = make_float2(cr, ci);
    float nx = mx * cr - my * ci + e.x;
    float ny = mx * ci + my * cr + e.y;
    cr = nx; ci = ny;
  }
  float Mx = mx, My = my;
#pragma unroll
  for (int k = 0; k < 3; ++k) {  // M = m^8
    float nx = Mx * Mx - My * My, ny = 2.f * Mx * My;
    Mx = nx; My = ny;
  }
  float Vx = cr, Vy = ci;
#pragma unroll
  for (int d = 1; d < 32; d <<= 1) {
    arr[rq][pl] = make_float2(Vx, Vy);
    __syncthreads();
    if (rq >= d) {
      float2 pv = arr[rq - d][pl];
      Vx += Mx * pv.x - My * pv.y;
      Vy += Mx * pv.y + My * pv.x;
    }
    __syncthreads();
    float nx = Mx * Mx - My * My, ny = 2.f * Mx * My;
    Mx = nx; My = ny;
  }
  arr[rq][pl] = make_float2(Vx, Vy);
  __syncthreads();
  float Cx = 0.f, Cy = 0.f;
  if (rq > 0) {
    float2 pv = arr[rq - 1][pl];
    Cx = pv.x; Cy = pv.y;
  }
  float tx = 1.f, ty = 0.f;
#pragma unroll
  for (int i = 0; i < 8; ++i) {
    float ox = pre[i].x + tx * Cx - ty * Cy;
    float oy = pre[i].y + tx * Cy + ty * Cx;
    E[base + (size_t)i * Pd] = make_float2(ox, oy);
    float nx = tx * mx - ty * my, ny = tx * my + ty * mx;
    tx = nx; ty = ny;
  }
}

// ---------------- kernel 3: main fused kernel, two 16-l halves ----------------
__global__ __launch_bounds__(256, 6) void k_main(
    const float* __restrict__ u, const float* __restrict__ lre,
    const float* __restrict__ lim, const bf16x8* __restrict__ Bfr,
    const bf16x8* __restrict__ Bfi, const bf16x8* __restrict__ Cf,
    const bf16x8* __restrict__ Df, const float2* __restrict__ E,
    float* __restrict__ out) {
  int bc = blockIdx.x;
  int b = bc >> 8, c = bc & 255;
  __shared__ __align__(16) unsigned char smem[4096 + 16384];
  unsigned* us32 = (unsigned*)smem;
  unsigned* xs32 = (unsigned*)(smem + 4096);
  int t = threadIdx.x;
  int lane = t & 63, w = t >> 6, q = lane >> 4, ln = lane & 15;
  int p = t;

  float2 xin = E[(size_t)bc * Pd + p];  // prefetch seed early
  float ax = lre[p], ay = lim[p];
  const float* ub = u + (size_t)b * Hd * Ld + c * LC;
  float xr = xin.x, xi = xin.y;

#pragma unroll
  for (int hf = 0; hf < 2; ++hf) {
    if (hf) __syncthreads();  // projection's cross-wave us/xs reads done
    stage_u16(ub + hf * LH, us32, t);
    __syncthreads();
    compute_bu16(us32, Bfr, Bfi, xs32, t);
    // same-wave capture + seeded scan, in-place rewrite (no barrier needed)
#pragma unroll
    for (int j = 0; j < LH; ++j) {
      int idx = xs_idx(p, j);
      unsigned v = xs32[idx];
      float sr = xr + bflo(v), si = xi + bfhi(v);
      xr = ax * sr - ay * si;
      xi = ax * si + ay * sr;
      xs32[idx] = pack2(xr, xi);
    }
    __syncthreads();  // xs scanned + us ready for cross-wave MFMA reads

    // projection: y = [Cre | -Cim] @ xs + D @ u for this half's 16 columns
    f32x4 zz = {0.f, 0.f, 0.f, 0.f};
    f32x4 acc[2] = {zz, zz};
#pragma unroll
    for (int ks = 0; ks < 16; ++ks) {
      int g = (4 * ks + q) ^ (ln & 7);
      bf16x8 xb = *(const bf16x8*)((const char*)xs32 + ln * 1024 + g * 16);
#pragma unroll
      for (int mt = 0; mt < 2; ++mt)
        acc[mt] = MFMA16(Cf[(ks * 8 + w * 2 + mt) * 64 + lane], xb, acc[mt]);
    }
#pragma unroll
    for (int ks = 0; ks < 4; ++ks) {
      int g = (4 * ks + q) ^ (ln & 7);
      bf16x8 ubf = *(const bf16x8*)((const char*)us32 + ln * 256 + g * 16);
#pragma unroll
      for (int mt = 0; mt < 2; ++mt)
        acc[mt] = MFMA16(Df[(ks * 8 + w * 2 + mt) * 64 + lane], ubf, acc[mt]);
    }

    // GELU (sigmoid form) + store
    int l = c * LC + hf * LH + ln;
#pragma unroll
    for (int mt = 0; mt < 2; ++mt)
#pragma unroll
      for (int r = 0; r < 4; ++r) {
        int o = w * 32 + mt * 16 + q * 4 + r;
        float vy = acc[mt][r];
        float e2 = __builtin_amdgcn_exp2f(-2.4554670f * vy);  // exp(-1.702 v)
        float gy = vy * __builtin_amdgcn_rcpf(1.0f + e2);
        out[((size_t)(b * Hd + o)) * Ld + l] = gy;
      }
  }
}

// ---------------- launch ----------------
extern "C" void kernel_launch(void* const* d_in, const int* in_sizes, int n_in,
                              void* d_out, int out_size, void* d_ws, size_t ws_size,
                              hipStream_t stream) {
  const float* u   = (const float*)d_in[0];
  const float* lre = (const float*)d_in[1];
  const float* lim = (const float*)d_in[2];
  const float* Bre = (const float*)d_in[3];
  const float* Bim = (const float*)d_in[4];
  const float* Cre = (const float*)d_in[5];
  const float* Cim = (const float*)d_in[6];
  const float* Dm  = (const float*)d_in[7];
  float* out = (float*)d_out;

  char* ws = (char*)d_ws;
  bf16x8* Bfr = (bf16x8*)(ws);                 // 64 KB
  bf16x8* Bfi = (bf16x8*)(ws + 65536);         // 64 KB
  bf16x8* Cf  = (bf16x8*)(ws + 131072);        // 128 KB
  bf16x8* Df  = (bf16x8*)(ws + 262144);        // 32 KB
  float2* E   = (float2*)(ws + (1 << 20));     // 4.19 MB

  k_prep<<<56, 256, 0, stream>>>(Bre, Bim, Cre, Cim, Dm, Bfr, Bfi, Cf, Df);
  k_chunk<<<Bn * NC, 256, 0, stream>>>(u, lre, lim, Bfr, Bfi, E);
  k_scan<<<256, 256, 0, stream>>>(lre, lim, E);
  k_main<<<Bn * NC, 256, 0, stream>>>(u, lre, lim, Bfr, Bfi, Cf, Df, E, out);
}

// Round 10
// 183.240 us; speedup vs baseline: 1.3003x; 1.3003x over previous
//
#include <hip/hip_runtime.h>
#include <math.h>

#define Bn 8
#define Hd 128
#define Ld 8192
#define Pd 256
#define LC 32
#define NC 256  // Ld / LC

typedef __attribute__((ext_vector_type(8))) short bf16x8;
typedef __attribute__((ext_vector_type(4))) float f32x4;
#define MFMA16(a, b, c) __builtin_amdgcn_mfma_f32_16x16x32_bf16(a, b, c, 0, 0, 0)

__device__ __forceinline__ unsigned short f2bf(float f) {
  unsigned u = __float_as_uint(f);
  u = u + 0x7fffu + ((u >> 16) & 1u);  // round-to-nearest-even
  return (unsigned short)(u >> 16);
}

#if __has_builtin(__builtin_amdgcn_cvt_pk_bf16_f32)
typedef __attribute__((ext_vector_type(2))) __bf16 v2bf_t;
__device__ __forceinline__ unsigned pack2(float a, float b) {
  v2bf_t r = __builtin_amdgcn_cvt_pk_bf16_f32(a, b);  // low = a, high = b
  unsigned u;
  __builtin_memcpy(&u, &r, 4);
  return u;
}
#else
__device__ __forceinline__ unsigned pack2(float a, float b) {
  return (unsigned)f2bf(a) | ((unsigned)f2bf(b) << 16);
}
#endif

__device__ __forceinline__ float bflo(unsigned v) { return __uint_as_float(v << 16); }
__device__ __forceinline__ float bfhi(unsigned v) { return __uint_as_float(v & 0xffff0000u); }

// ---- half-P compact layout --------------------------------------------------
// p belongs to half h iff ((p>>5)&1)==h. Compact index pt = ((p>>6)<<5)|(p&31).
// Half-xs: [32 j][128 pt] words (16 KB). Slot:
//   word = j*128 + (((pt>>2) ^ (j&7)) << 2) | (pt&3)
// Banks: b128 C-frag stores uniform 8 lanes/bank-quad; per-pt scan (32 active
// lanes/wave) hits 32 distinct banks; proj xb reads uniform. All conflict-free
// or 2-way (free per m136).
__device__ __forceinline__ int xsh_idx(int pt, int j) {
  return j * 128 + ((((pt >> 2) ^ (j & 7)) << 2) | (pt & 3));
}

// ---------------- kernel 0: repack B,C,D into MFMA A-fragment order ----------------
__global__ void k_prep(const float* __restrict__ Bre, const float* __restrict__ Bim,
                       const float* __restrict__ Cre, const float* __restrict__ Cim,
                       const float* __restrict__ Dm,
                       bf16x8* __restrict__ Bfr, bf16x8* __restrict__ Bfi,
                       bf16x8* __restrict__ Cf, bf16x8* __restrict__ Df) {
  int tid = blockIdx.x * 256 + threadIdx.x;
  int lane = tid & 63, slot = tid >> 6;
  int q = lane >> 4, ln = lane & 15;
  if (slot < 64) {  // B tables
    int ks = slot >> 4, mt = slot & 15;
    int p = mt * 16 + ln;
    bf16x8 vr, vi;
#pragma unroll
    for (int e = 0; e < 8; ++e) {
      int h = ks * 32 + q * 8 + e;
      vr[e] = (short)f2bf(Bre[p * Hd + h]);
      vi[e] = (short)f2bf(Bim[p * Hd + h]);
    }
    Bfr[slot * 64 + lane] = vr;
    Bfi[slot * 64 + lane] = vi;
  } else if (slot < 64 + 128) {  // C table, K' = 512 interleaved (re, -im)
    int s2 = slot - 64;
    int ks = s2 >> 3, mt = s2 & 7;
    int o = mt * 16 + ln;
    bf16x8 v;
#pragma unroll
    for (int e = 0; e < 8; ++e) {
      int kp = ks * 32 + q * 8 + e;
      int p = kp >> 1;
      float val = (kp & 1) ? -Cim[o * Pd + p] : Cre[o * Pd + p];
      v[e] = (short)f2bf(val);
    }
    Cf[s2 * 64 + lane] = v;
  } else if (slot < 64 + 128 + 32) {  // D table
    int s3 = slot - 192;
    int ks = s3 >> 3, mt = s3 & 7;
    int o = mt * 16 + ln;
    bf16x8 v;
#pragma unroll
    for (int e = 0; e < 8; ++e) {
      int h = ks * 32 + q * 8 + e;
      v[e] = (short)f2bf(Dm[o * Hd + h]);
    }
    Df[s3 * 64 + lane] = v;
  }
}

// ---- u staging: 32 rows (j) x 128 bf16 (h), 256 B/row, XOR-swizzled 16B granules
// (unchanged from r8: 128B-contiguous global reads per lane-quad)
__device__ __forceinline__ void stage_u(const float* __restrict__ ub, unsigned* us32, int t) {
  int lane = t & 63, w = t >> 6;
  int j0 = 4 * (lane & 7);
  int h2 = 16 * w + 2 * (lane >> 3);
  const float* r0 = ub + (size_t)h2 * Ld + j0;
  float4 a0 = *(const float4*)r0;
  float4 a1 = *(const float4*)(r0 + Ld);
  const float* r2 = r0 + (size_t)64 * Ld;
  float4 b0 = *(const float4*)r2;
  float4 b1 = *(const float4*)(r2 + Ld);
  float ta0[4] = {a0.x, a0.y, a0.z, a0.w};
  float ta1[4] = {a1.x, a1.y, a1.z, a1.w};
  float tb0[4] = {b0.x, b0.y, b0.z, b0.w};
  float tb1[4] = {b1.x, b1.y, b1.z, b1.w};
#pragma unroll
  for (int i = 0; i < 4; ++i) {
    int j = j0 + i;
    int g1 = (h2 >> 3) ^ (j & 7);
    us32[(j * 256 + (g1 << 4) + ((2 * h2) & 15)) >> 2] = pack2(ta0[i], ta1[i]);
    int hb = h2 + 64;
    int g2 = (hb >> 3) ^ (j & 7);
    us32[(j * 256 + (g2 << 4) + ((2 * hb) & 15)) >> 2] = pack2(tb0[i], tb1[i]);
  }
}

// Bu half-pass: p-set h = {p: (p>>5)&1 == h}. Wave w computes its own compact
// rows pt in [w*32, w*32+32) -> later per-thread capture is SAME-WAVE.
// B-table tile: tI = ks*16 + w*4 + h*2 + mt (table unchanged).
__device__ __forceinline__ void compute_bu_half(const unsigned* us32,
                                                const bf16x8* __restrict__ Bfr,
                                                const bf16x8* __restrict__ Bfi,
                                                unsigned* xs16, int t, int h) {
  int lane = t & 63, w = t >> 6, q = lane >> 4, ln = lane & 15;
  f32x4 zz = {0.f, 0.f, 0.f, 0.f};
  f32x4 aR[2][2], aI[2][2];
#pragma unroll
  for (int mt = 0; mt < 2; ++mt)
#pragma unroll
    for (int n = 0; n < 2; ++n) { aR[mt][n] = zz; aI[mt][n] = zz; }

#pragma unroll
  for (int ks = 0; ks < 4; ++ks) {
    bf16x8 ubf[2];
#pragma unroll
    for (int n = 0; n < 2; ++n) {
      int j = 16 * n + ln;
      int g = (4 * ks + q) ^ (j & 7);
      ubf[n] = *(const bf16x8*)((const char*)us32 + j * 256 + g * 16);
    }
#pragma unroll
    for (int mt = 0; mt < 2; ++mt) {
      int tI = ks * 16 + w * 4 + h * 2 + mt;
      bf16x8 ar = Bfr[tI * 64 + lane];
      bf16x8 ai = Bfi[tI * 64 + lane];
#pragma unroll
      for (int n = 0; n < 2; ++n) {
        aR[mt][n] = MFMA16(ar, ubf[n], aR[mt][n]);
        aI[mt][n] = MFMA16(ai, ubf[n], aI[mt][n]);
      }
    }
  }
  // b128 stores into half-xs: pt0 = w*32 + mt*16 + q*4 (4 consecutive words)
#pragma unroll
  for (int mt = 0; mt < 2; ++mt)
#pragma unroll
    for (int n = 0; n < 2; ++n) {
      int ptq = (w << 3) | (mt << 2) | q;  // pt0 >> 2
      int j = 16 * n + ln;
      int g = ptq ^ (j & 7);
      uint4 wv = make_uint4(pack2(aR[mt][n][0], aI[mt][n][0]),
                            pack2(aR[mt][n][1], aI[mt][n][1]),
                            pack2(aR[mt][n][2], aI[mt][n][2]),
                            pack2(aR[mt][n][3], aI[mt][n][3]));
      *(uint4*)(xs16 + j * 128 + g * 4) = wv;
    }
}

// ---------------- kernel 1: per-chunk state contribution E ----------------
// LDS 24 KB -> 6 blocks/CU. Two half-P passes; capture is same-wave, scan-total
// only (no xs write-back). ONE barrier total.
__global__ __launch_bounds__(256, 6) void k_chunk(
    const float* __restrict__ u, const float* __restrict__ lre,
    const float* __restrict__ lim, const bf16x8* __restrict__ Bfr,
    const bf16x8* __restrict__ Bfi, float2* __restrict__ E) {
  int bc = blockIdx.x;
  int b = bc >> 8, c = bc & 255;
  __shared__ __align__(16) unsigned char smem[8192 + 16384];
  unsigned* us32 = (unsigned*)smem;
  unsigned* xs16 = (unsigned*)(smem + 8192);
  int t = threadIdx.x;
  int p = t;
  int hme = (t >> 5) & 1;                 // which half-pass owns this thread's p
  int pt = ((t >> 6) << 5) | (t & 31);    // compact index
  float ax = lre[p], ay = lim[p];

  stage_u(u + (size_t)b * Hd * Ld + c * LC, us32, t);
  __syncthreads();

  float xr = 0.f, xi = 0.f;
#pragma unroll
  for (int h = 0; h < 2; ++h) {
    compute_bu_half(us32, Bfr, Bfi, xs16, t, h);
    // same-wave capture (half the lanes active); bu of next half overwrites
    // the same wave-owned rows -> program order within wave, no barrier.
    if (hme == h) {
#pragma unroll
      for (int j = 0; j < LC; ++j) {
        unsigned v = xs16[xsh_idx(pt, j)];
        float sr = xr + bflo(v), si = xi + bfhi(v);
        xr = ax * sr - ay * si;
        xi = ax * si + ay * sr;
      }
    }
  }
  E[(size_t)bc * Pd + p] = make_float2(xr, xi);
}

// ---------------- kernel 2: parallel prefix scan over chunks ----------------
__global__ __launch_bounds__(256) void k_scan(const float* __restrict__ lre,
                                              const float* __restrict__ lim,
                                              float2* __restrict__ E) {
  __shared__ float2 arr[32][8];
  int nb = blockIdx.x;  // 0..255
  int t = threadIdx.x;
  int pl = t & 7, rq = t >> 3;  // rq = run index 0..31
  int b = nb >> 5;
  int p = ((nb & 31) << 3) + pl;
  float ax = lre[p], ay = lim[p];
  float mx = ax, my = ay;
#pragma unroll
  for (int k = 0; k < 5; ++k) {  // m = a^32
    float nx = mx * mx - my * my, ny = 2.f * mx * my;
    mx = nx; my = ny;
  }
  size_t base = ((size_t)(b * NC + rq * 8)) * Pd + p;
  float2 pre[8];
  float cr = 0.f, ci = 0.f;
#pragma unroll
  for (int i = 0; i < 8; ++i) {
    float2 e = E[base + (size_t)i * Pd];
    pre[i] = make_float2(cr, ci);
    float nx = mx * cr - my * ci + e.x;
    float ny = mx * ci + my * cr + e.y;
    cr = nx; ci = ny;
  }
  float Mx = mx, My = my;
#pragma unroll
  for (int k = 0; k < 3; ++k) {  // M = m^8
    float nx = Mx * Mx - My * My, ny = 2.f * Mx * My;
    Mx = nx; My = ny;
  }
  float Vx = cr, Vy = ci;
#pragma unroll
  for (int d = 1; d < 32; d <<= 1) {
    arr[rq][pl] = make_float2(Vx, Vy);
    __syncthreads();
    if (rq >= d) {
      float2 pv = arr[rq - d][pl];
      Vx += Mx * pv.x - My * pv.y;
      Vy += Mx * pv.y + My * pv.x;
    }
    __syncthreads();
    float nx = Mx * Mx - My * My, ny = 2.f * Mx * My;
    Mx = nx; My = ny;
  }
  arr[rq][pl] = make_float2(Vx, Vy);
  __syncthreads();
  float Cx = 0.f, Cy = 0.f;
  if (rq > 0) {
    float2 pv = arr[rq - 1][pl];
    Cx = pv.x; Cy = pv.y;
  }
  float tx = 1.f, ty = 0.f;
#pragma unroll
  for (int i = 0; i < 8; ++i) {
    float ox = pre[i].x + tx * Cx - ty * Cy;
    float oy = pre[i].y + tx * Cy + ty * Cx;
    E[base + (size_t)i * Pd] = make_float2(ox, oy);
    float nx = tx * mx - ty * my, ny = tx * my + ty * mx;
    tx = nx; ty = ny;
  }
}

// ---------------- kernel 3: main fused kernel, two half-P passes ----------------
// LDS 24 KB -> up to 6 blocks/CU. Projection accumulates over both halves via
// the matching K'-slices (ks with (ks>>1)&1 == h); Cf table unchanged.
__global__ __launch_bounds__(256, 4) void k_main(
    const float* __restrict__ u, const float* __restrict__ lre,
    const float* __restrict__ lim, const bf16x8* __restrict__ Bfr,
    const bf16x8* __restrict__ Bfi, const bf16x8* __restrict__ Cf,
    const bf16x8* __restrict__ Df, const float2* __restrict__ E,
    float* __restrict__ out) {
  int bc = blockIdx.x;
  int b = bc >> 8, c = bc & 255;
  __shared__ __align__(16) unsigned char smem[8192 + 16384];
  unsigned* us32 = (unsigned*)smem;
  unsigned* xs16 = (unsigned*)(smem + 8192);
  int t = threadIdx.x;
  int lane = t & 63, w = t >> 6, q = lane >> 4, ln = lane & 15;
  int p = t;
  int hme = (t >> 5) & 1;
  int pt = ((t >> 6) << 5) | (t & 31);

  float2 xin = E[(size_t)bc * Pd + p];  // prefetch seed early
  float ax = lre[p], ay = lim[p];

  stage_u(u + (size_t)b * Hd * Ld + c * LC, us32, t);
  __syncthreads();

  f32x4 zz = {0.f, 0.f, 0.f, 0.f};
  f32x4 acc[2][2] = {{zz, zz}, {zz, zz}};
  float xr = xin.x, xi = xin.y;

#pragma unroll
  for (int h = 0; h < 2; ++h) {
    if (h) __syncthreads();  // proj(h-1) xs reads done before overwrite
    compute_bu_half(us32, Bfr, Bfi, xs16, t, h);
    // same-wave capture + seeded scan, in-place rewrite (half the lanes)
    if (hme == h) {
#pragma unroll
      for (int j = 0; j < LC; ++j) {
        int idx = xsh_idx(pt, j);
        unsigned v = xs16[idx];
        float sr = xr + bflo(v), si = xi + bfhi(v);
        xr = ax * sr - ay * si;
        xi = ax * si + ay * sr;
        xs16[idx] = pack2(xr, xi);
      }
    }
    __syncthreads();  // scanned half-xs visible to all waves

    // projection: the 8 K'-slices whose p's live in this half
#pragma unroll
    for (int ksl = 0; ksl < 8; ++ksl) {
      int ks = ((ksl >> 1) << 2) | (h << 1) | (ksl & 1);
      int gb = ((ks >> 2) << 3) | ((ks & 1) << 2) | q;
      bf16x8 xb[2];
#pragma unroll
      for (int n = 0; n < 2; ++n) {
        int j = 16 * n + ln;
        int g = gb ^ (j & 7);
        xb[n] = *(const bf16x8*)((const char*)xs16 + j * 512 + g * 16);
      }
#pragma unroll
      for (int mt = 0; mt < 2; ++mt) {
        bf16x8 cf = Cf[(ks * 8 + w * 2 + mt) * 64 + lane];
#pragma unroll
        for (int n = 0; n < 2; ++n) acc[mt][n] = MFMA16(cf, xb[n], acc[mt][n]);
      }
    }
  }

  // D @ u (us untouched since stage)
#pragma unroll
  for (int ks = 0; ks < 4; ++ks) {
    bf16x8 ubf[2];
#pragma unroll
    for (int n = 0; n < 2; ++n) {
      int j = 16 * n + ln;
      int g = (4 * ks + q) ^ (j & 7);
      ubf[n] = *(const bf16x8*)((const char*)us32 + j * 256 + g * 16);
    }
#pragma unroll
    for (int mt = 0; mt < 2; ++mt) {
      bf16x8 df = Df[(ks * 8 + w * 2 + mt) * 64 + lane];
#pragma unroll
      for (int n = 0; n < 2; ++n) acc[mt][n] = MFMA16(df, ubf[n], acc[mt][n]);
    }
  }

  // ---- GELU (sigmoid form) + store (128B-contiguous per lane-quad) ----
#pragma unroll
  for (int mt = 0; mt < 2; ++mt)
#pragma unroll
    for (int n = 0; n < 2; ++n)
#pragma unroll
      for (int r = 0; r < 4; ++r) {
        int o = w * 32 + mt * 16 + q * 4 + r;
        int l = c * LC + 16 * n + ln;
        float vy = acc[mt][n][r];
        float e2 = __builtin_amdgcn_exp2f(-2.4554670f * vy);  // exp(-1.702 v)
        float gy = vy * __builtin_amdgcn_rcpf(1.0f + e2);
        out[((size_t)(b * Hd + o)) * Ld + l] = gy;
      }
}

// ---------------- launch ----------------
extern "C" void kernel_launch(void* const* d_in, const int* in_sizes, int n_in,
                              void* d_out, int out_size, void* d_ws, size_t ws_size,
                              hipStream_t stream) {
  const float* u   = (const float*)d_in[0];
  const float* lre = (const float*)d_in[1];
  const float* lim = (const float*)d_in[2];
  const float* Bre = (const float*)d_in[3];
  const float* Bim = (const float*)d_in[4];
  const float* Cre = (const float*)d_in[5];
  const float* Cim = (const float*)d_in[6];
  const float* Dm  = (const float*)d_in[7];
  float* out = (float*)d_out;

  char* ws = (char*)d_ws;
  bf16x8* Bfr = (bf16x8*)(ws);                 // 64 KB
  bf16x8* Bfi = (bf16x8*)(ws + 65536);         // 64 KB
  bf16x8* Cf  = (bf16x8*)(ws + 131072);        // 128 KB
  bf16x8* Df  = (bf16x8*)(ws + 262144);        // 32 KB
  float2* E   = (float2*)(ws + (1 << 20));     // 4.19 MB

  k_prep<<<56, 256, 0, stream>>>(Bre, Bim, Cre, Cim, Dm, Bfr, Bfi, Cf, Df);
  k_chunk<<<Bn * NC, 256, 0, stream>>>(u, lre, lim, Bfr, Bfi, E);
  k_scan<<<256, 256, 0, stream>>>(lre, lim, E);
  k_main<<<Bn * NC, 256, 0, stream>>>(u, lre, lim, Bfr, Bfi, Cf, Df, E, out);
}

// Round 11
// 147.357 us; speedup vs baseline: 1.6170x; 1.2435x over previous
//
#include <hip/hip_runtime.h>
#include <math.h>

#define Bn 8
#define Hd 128
#define Ld 8192
#define Pd 256
#define LC 32
#define NC 256  // Ld / LC

typedef __attribute__((ext_vector_type(8))) short bf16x8;
typedef __attribute__((ext_vector_type(4))) float f32x4;
#define MFMA16(a, b, c) __builtin_amdgcn_mfma_f32_16x16x32_bf16(a, b, c, 0, 0, 0)

__device__ __forceinline__ unsigned short f2bf(float f) {
  unsigned u = __float_as_uint(f);
  u = u + 0x7fffu + ((u >> 16) & 1u);  // round-to-nearest-even
  return (unsigned short)(u >> 16);
}

#if __has_builtin(__builtin_amdgcn_cvt_pk_bf16_f32)
typedef __attribute__((ext_vector_type(2))) __bf16 v2bf_t;
__device__ __forceinline__ unsigned pack2(float a, float b) {
  v2bf_t r = __builtin_amdgcn_cvt_pk_bf16_f32(a, b);  // low = a, high = b
  unsigned u;
  __builtin_memcpy(&u, &r, 4);
  return u;
}
#else
__device__ __forceinline__ unsigned pack2(float a, float b) {
  return (unsigned)f2bf(a) | ((unsigned)f2bf(b) << 16);
}
#endif

__device__ __forceinline__ float bflo(unsigned v) { return __uint_as_float(v << 16); }
__device__ __forceinline__ float bfhi(unsigned v) { return __uint_as_float(v & 0xffff0000u); }

// xs-layout slot for (p, j): word index j*256 + ((p>>2)^(j&7))*4 + (p&3).
// b128 C-frag stores: 8 words/bank (conflict-free min); per-p scan: 2-way (free).
__device__ __forceinline__ int xs_idx(int p, int j) {
  return j * 256 + ((((p >> 2) ^ (j & 7)) << 2) | (p & 3));
}

// ---------------- kernel 0: repack B,C,D into MFMA A-fragment order ----------------
__global__ void k_prep(const float* __restrict__ Bre, const float* __restrict__ Bim,
                       const float* __restrict__ Cre, const float* __restrict__ Cim,
                       const float* __restrict__ Dm,
                       bf16x8* __restrict__ Bfr, bf16x8* __restrict__ Bfi,
                       bf16x8* __restrict__ Cf, bf16x8* __restrict__ Df) {
  int tid = blockIdx.x * 256 + threadIdx.x;
  int lane = tid & 63, slot = tid >> 6;
  int q = lane >> 4, ln = lane & 15;
  if (slot < 64) {  // B tables
    int ks = slot >> 4, mt = slot & 15;
    int p = mt * 16 + ln;
    bf16x8 vr, vi;
#pragma unroll
    for (int e = 0; e < 8; ++e) {
      int h = ks * 32 + q * 8 + e;
      vr[e] = (short)f2bf(Bre[p * Hd + h]);
      vi[e] = (short)f2bf(Bim[p * Hd + h]);
    }
    Bfr[slot * 64 + lane] = vr;
    Bfi[slot * 64 + lane] = vi;
  } else if (slot < 64 + 128) {  // C table, K' = 512 interleaved (re, -im)
    int s2 = slot - 64;
    int ks = s2 >> 3, mt = s2 & 7;
    int o = mt * 16 + ln;
    bf16x8 v;
#pragma unroll
    for (int e = 0; e < 8; ++e) {
      int kp = ks * 32 + q * 8 + e;
      int p = kp >> 1;
      float val = (kp & 1) ? -Cim[o * Pd + p] : Cre[o * Pd + p];
      v[e] = (short)f2bf(val);
    }
    Cf[s2 * 64 + lane] = v;
  } else if (slot < 64 + 128 + 32) {  // D table
    int s3 = slot - 192;
    int ks = s3 >> 3, mt = s3 & 7;
    int o = mt * 16 + ln;
    bf16x8 v;
#pragma unroll
    for (int e = 0; e < 8; ++e) {
      int h = ks * 32 + q * 8 + e;
      v[e] = (short)f2bf(Dm[o * Hd + h]);
    }
    Df[s3 * 64 + lane] = v;
  }
}

// ---- u staging: 32 rows (j) x 128 bf16 (h), 256 B/row, XOR-swizzled 16B granules
// 128B-contiguous global reads per lane-quad.
__device__ __forceinline__ void stage_u(const float* __restrict__ ub, unsigned* us32, int t) {
  int lane = t & 63, w = t >> 6;
  int j0 = 4 * (lane & 7);
  int h2 = 16 * w + 2 * (lane >> 3);
  const float* r0 = ub + (size_t)h2 * Ld + j0;
  float4 a0 = *(const float4*)r0;
  float4 a1 = *(const float4*)(r0 + Ld);
  const float* r2 = r0 + (size_t)64 * Ld;
  float4 b0 = *(const float4*)r2;
  float4 b1 = *(const float4*)(r2 + Ld);
  float ta0[4] = {a0.x, a0.y, a0.z, a0.w};
  float ta1[4] = {a1.x, a1.y, a1.z, a1.w};
  float tb0[4] = {b0.x, b0.y, b0.z, b0.w};
  float tb1[4] = {b1.x, b1.y, b1.z, b1.w};
#pragma unroll
  for (int i = 0; i < 4; ++i) {
    int j = j0 + i;
    int g1 = (h2 >> 3) ^ (j & 7);
    us32[(j * 256 + (g1 << 4) + ((2 * h2) & 15)) >> 2] = pack2(ta0[i], ta1[i]);
    int hb = h2 + 64;
    int g2 = (hb >> 3) ^ (j & 7);
    us32[(j * 256 + (g2 << 4) + ((2 * hb) & 15)) >> 2] = pack2(tb0[i], tb1[i]);
  }
}

// Bu = B_bar @ u_tile via MFMA; stores packed bf16 (re,im) DIRECTLY in the xs
// layout via b128 (4 acc rows r=0..3 = 4 consecutive words). Wave w covers
// p in [64w,64w+64) -> thread p's later capture is same-wave (no barrier).
__device__ __forceinline__ void compute_bu(const unsigned* us32,
                                           const bf16x8* __restrict__ Bfr,
                                           const bf16x8* __restrict__ Bfi,
                                           unsigned* xs32, int t) {
  int lane = t & 63, w = t >> 6, q = lane >> 4, ln = lane & 15;
  f32x4 zz = {0.f, 0.f, 0.f, 0.f};
  f32x4 aR[4][2], aI[4][2];
#pragma unroll
  for (int mt = 0; mt < 4; ++mt)
#pragma unroll
    for (int n = 0; n < 2; ++n) { aR[mt][n] = zz; aI[mt][n] = zz; }

#pragma unroll
  for (int ks = 0; ks < 4; ++ks) {
    bf16x8 ubf[2];
#pragma unroll
    for (int n = 0; n < 2; ++n) {
      int j = 16 * n + ln;
      int g = (4 * ks + q) ^ (j & 7);
      ubf[n] = *(const bf16x8*)((const char*)us32 + j * 256 + g * 16);
    }
#pragma unroll
    for (int mt = 0; mt < 4; ++mt) {
      int tI = ks * 16 + w * 4 + mt;
      bf16x8 ar = Bfr[tI * 64 + lane];
      bf16x8 ai = Bfi[tI * 64 + lane];
#pragma unroll
      for (int n = 0; n < 2; ++n) {
        aR[mt][n] = MFMA16(ar, ubf[n], aR[mt][n]);
        aI[mt][n] = MFMA16(ai, ubf[n], aI[mt][n]);
      }
    }
  }
#pragma unroll
  for (int mt = 0; mt < 4; ++mt)
#pragma unroll
    for (int n = 0; n < 2; ++n) {
      int p0 = w * 64 + mt * 16 + q * 4;  // p0 % 4 == 0; rows r = 0..3
      int j = 16 * n + ln;
      int g = (p0 >> 2) ^ (j & 7);
      uint4 wv = make_uint4(pack2(aR[mt][n][0], aI[mt][n][0]),
                            pack2(aR[mt][n][1], aI[mt][n][1]),
                            pack2(aR[mt][n][2], aI[mt][n][2]),
                            pack2(aR[mt][n][3], aI[mt][n][3]));
      *(uint4*)(xs32 + j * 256 + g * 4) = wv;  // 16B-aligned b128
    }
}

// ---------------- kernel 1: chunk-local everything (Bu computed ONCE) ----------------
// stage + Bu + zero-seeded in-place scan -> xs0; chunk total -> E;
// projection partial0 = C'@xs0 + D@u -> P0 (packed bf16, THREAD-MAJOR:
// thread t owns 32B contiguous at P0v[bc*512 + t*2] -- perfect granules).
__global__ __launch_bounds__(256, 4) void k_chunkP(
    const float* __restrict__ u, const float* __restrict__ lre,
    const float* __restrict__ lim, const bf16x8* __restrict__ Bfr,
    const bf16x8* __restrict__ Bfi, const bf16x8* __restrict__ Cf,
    const bf16x8* __restrict__ Df, float2* __restrict__ E,
    uint4* __restrict__ P0v) {
  int bc = blockIdx.x;
  int b = bc >> 8, c = bc & 255;
  __shared__ __align__(16) unsigned char smem[8192 + 32768];
  unsigned* us32 = (unsigned*)smem;
  unsigned* xs32 = (unsigned*)(smem + 8192);
  int t = threadIdx.x;
  int lane = t & 63, w = t >> 6, q = lane >> 4, ln = lane & 15;
  int p = t;
  float ax = lre[p], ay = lim[p];

  stage_u(u + (size_t)b * Hd * Ld + c * LC, us32, t);
  __syncthreads();
  compute_bu(us32, Bfr, Bfi, xs32, t);

  // same-wave capture + ZERO-seeded scan, in-place rewrite (no barrier needed)
  {
    float xr = 0.f, xi = 0.f;
#pragma unroll
    for (int j = 0; j < LC; ++j) {
      int idx = xs_idx(p, j);
      unsigned v = xs32[idx];
      float sr = xr + bflo(v), si = xi + bfhi(v);
      xr = ax * sr - ay * si;
      xi = ax * si + ay * sr;
      xs32[idx] = pack2(xr, xi);
    }
    E[(size_t)bc * Pd + p] = make_float2(xr, xi);  // zero-seeded chunk total
  }
  __syncthreads();  // xs0 + us ready for cross-wave MFMA reads

  // ---- projection: partial0 = [Cre | -Cim] @ xs0 + D @ u ----
  f32x4 zz = {0.f, 0.f, 0.f, 0.f};
  f32x4 acc[2][2] = {{zz, zz}, {zz, zz}};
#pragma unroll
  for (int ks = 0; ks < 16; ++ks) {
    bf16x8 xb[2];
#pragma unroll
    for (int n = 0; n < 2; ++n) {
      int j = 16 * n + ln;
      int g = (4 * ks + q) ^ (j & 7);
      xb[n] = *(const bf16x8*)((const char*)xs32 + j * 1024 + g * 16);
    }
#pragma unroll
    for (int mt = 0; mt < 2; ++mt) {
      bf16x8 cf = Cf[(ks * 8 + w * 2 + mt) * 64 + lane];
#pragma unroll
      for (int n = 0; n < 2; ++n) acc[mt][n] = MFMA16(cf, xb[n], acc[mt][n]);
    }
  }
#pragma unroll
  for (int ks = 0; ks < 4; ++ks) {
    bf16x8 ubf[2];
#pragma unroll
    for (int n = 0; n < 2; ++n) {
      int j = 16 * n + ln;
      int g = (4 * ks + q) ^ (j & 7);
      ubf[n] = *(const bf16x8*)((const char*)us32 + j * 256 + g * 16);
    }
#pragma unroll
    for (int mt = 0; mt < 2; ++mt) {
      bf16x8 df = Df[(ks * 8 + w * 2 + mt) * 64 + lane];
#pragma unroll
      for (int n = 0; n < 2; ++n) acc[mt][n] = MFMA16(df, ubf[n], acc[mt][n]);
    }
  }

  // ---- P0 store: thread-major, packed bf16 (n=0,n=1 pair per word) ----
  uint4* dst = P0v + (size_t)bc * 512 + t * 2;
#pragma unroll
  for (int mt = 0; mt < 2; ++mt)
    dst[mt] = make_uint4(pack2(acc[mt][0][0], acc[mt][1][0]),
                         pack2(acc[mt][0][1], acc[mt][1][1]),
                         pack2(acc[mt][0][2], acc[mt][1][2]),
                         pack2(acc[mt][0][3], acc[mt][1][3]));
}

// ---------------- kernel 2: parallel prefix scan over chunks ----------------
__global__ __launch_bounds__(256) void k_scan(const float* __restrict__ lre,
                                              const float* __restrict__ lim,
                                              float2* __restrict__ E) {
  __shared__ float2 arr[32][8];
  int nb = blockIdx.x;  // 0..255
  int t = threadIdx.x;
  int pl = t & 7, rq = t >> 3;  // rq = run index 0..31
  int b = nb >> 5;
  int p = ((nb & 31) << 3) + pl;
  float ax = lre[p], ay = lim[p];
  float mx = ax, my = ay;
#pragma unroll
  for (int k = 0; k < 5; ++k) {  // m = a^32
    float nx = mx * mx - my * my, ny = 2.f * mx * my;
    mx = nx; my = ny;
  }
  size_t base = ((size_t)(b * NC + rq * 8)) * Pd + p;
  float2 pre[8];
  float cr = 0.f, ci = 0.f;
#pragma unroll
  for (int i = 0; i < 8; ++i) {
    float2 e = E[base + (size_t)i * Pd];
    pre[i] = make_float2(cr, ci);
    float nx = mx * cr - my * ci + e.x;
    float ny = mx * ci + my * cr + e.y;
    cr = nx; ci = ny;
  }
  float Mx = mx, My = my;
#pragma unroll
  for (int k = 0; k < 3; ++k) {  // M = m^8
    float nx = Mx * Mx - My * My, ny = 2.f * Mx * My;
    Mx = nx; My = ny;
  }
  float Vx = cr, Vy = ci;
#pragma unroll
  for (int d = 1; d < 32; d <<= 1) {
    arr[rq][pl] = make_float2(Vx, Vy);
    __syncthreads();
    if (rq >= d) {
      float2 pv = arr[rq - d][pl];
      Vx += Mx * pv.x - My * pv.y;
      Vy += Mx * pv.y + My * pv.x;
    }
    __syncthreads();
    float nx = Mx * Mx - My * My, ny = 2.f * Mx * My;
    Mx = nx; My = ny;
  }
  arr[rq][pl] = make_float2(Vx, Vy);
  __syncthreads();
  float Cx = 0.f, Cy = 0.f;
  if (rq > 0) {
    float2 pv = arr[rq - 1][pl];
    Cx = pv.x; Cy = pv.y;
  }
  float tx = 1.f, ty = 0.f;
#pragma unroll
  for (int i = 0; i < 8; ++i) {
    float ox = pre[i].x + tx * Cx - ty * Cy;
    float oy = pre[i].y + tx * Cy + ty * Cx;
    E[base + (size_t)i * Pd] = make_float2(ox, oy);
    float nx = tx * mx - ty * my, ny = tx * my + ty * mx;
    tx = nx; ty = ny;
  }
}

// ---------------- kernel 3: seed correction + GELU ----------------
// out = GELU(partial0 + C' @ corr), corr[p][j] = a_p^{j+1} * X_in[p].
// No u, no Bu, no D. LDS 32 KB -> 5 blocks/CU. P0 loads issued first
// (latency hides under corr chain + MFMAs).
__global__ __launch_bounds__(256, 4) void k_main2(
    const float* __restrict__ lre, const float* __restrict__ lim,
    const bf16x8* __restrict__ Cf, const float2* __restrict__ E,
    const uint4* __restrict__ P0v, float* __restrict__ out) {
  int bc = blockIdx.x;
  int b = bc >> 8, c = bc & 255;
  __shared__ __align__(16) unsigned xs32[LC * 256];  // 32 KB corr in xs layout
  int t = threadIdx.x;
  int lane = t & 63, w = t >> 6, q = lane >> 4, ln = lane & 15;
  int p = t;

  // issue P0 loads first (consumed only at the GELU epilogue)
  const uint4* src = P0v + (size_t)bc * 512 + t * 2;
  uint4 pA = src[0];
  uint4 pB = src[1];
  float2 xin = E[(size_t)bc * Pd + p];
  float ax = lre[p], ay = lim[p];

  // corr chain: g_j = a^{j+1} * X_in, packed bf16 into the xs layout
  float gr = ax * xin.x - ay * xin.y;
  float gi = ax * xin.y + ay * xin.x;
#pragma unroll
  for (int j = 0; j < LC; ++j) {
    xs32[xs_idx(p, j)] = pack2(gr, gi);
    float nr = ax * gr - ay * gi, ni = ax * gi + ay * gr;
    gr = nr; gi = ni;
  }
  __syncthreads();

  // C' @ corr
  f32x4 zz = {0.f, 0.f, 0.f, 0.f};
  f32x4 acc[2][2] = {{zz, zz}, {zz, zz}};
#pragma unroll
  for (int ks = 0; ks < 16; ++ks) {
    bf16x8 xb[2];
#pragma unroll
    for (int n = 0; n < 2; ++n) {
      int j = 16 * n + ln;
      int g = (4 * ks + q) ^ (j & 7);
      xb[n] = *(const bf16x8*)((const char*)xs32 + j * 1024 + g * 16);
    }
#pragma unroll
    for (int mt = 0; mt < 2; ++mt) {
      bf16x8 cf = Cf[(ks * 8 + w * 2 + mt) * 64 + lane];
#pragma unroll
      for (int n = 0; n < 2; ++n) acc[mt][n] = MFMA16(cf, xb[n], acc[mt][n]);
    }
  }

  // add partial0 (unpack), GELU (sigmoid form), store (128B/lane-quad)
  unsigned pw[2][4] = {{pA.x, pA.y, pA.z, pA.w}, {pB.x, pB.y, pB.z, pB.w}};
#pragma unroll
  for (int mt = 0; mt < 2; ++mt)
#pragma unroll
    for (int n = 0; n < 2; ++n)
#pragma unroll
      for (int r = 0; r < 4; ++r) {
        int o = w * 32 + mt * 16 + q * 4 + r;
        int l = c * LC + 16 * n + ln;
        float pv = n ? bfhi(pw[mt][r]) : bflo(pw[mt][r]);
        float vy = acc[mt][n][r] + pv;
        float e2 = __builtin_amdgcn_exp2f(-2.4554670f * vy);  // exp(-1.702 v)
        float gy = vy * __builtin_amdgcn_rcpf(1.0f + e2);
        out[((size_t)(b * Hd + o)) * Ld + l] = gy;
      }
}

// ---------------- launch ----------------
extern "C" void kernel_launch(void* const* d_in, const int* in_sizes, int n_in,
                              void* d_out, int out_size, void* d_ws, size_t ws_size,
                              hipStream_t stream) {
  const float* u   = (const float*)d_in[0];
  const float* lre = (const float*)d_in[1];
  const float* lim = (const float*)d_in[2];
  const float* Bre = (const float*)d_in[3];
  const float* Bim = (const float*)d_in[4];
  const float* Cre = (const float*)d_in[5];
  const float* Cim = (const float*)d_in[6];
  const float* Dm  = (const float*)d_in[7];
  float* out = (float*)d_out;

  char* ws = (char*)d_ws;
  bf16x8* Bfr = (bf16x8*)(ws);                 // 64 KB
  bf16x8* Bfi = (bf16x8*)(ws + 65536);         // 64 KB
  bf16x8* Cf  = (bf16x8*)(ws + 131072);        // 128 KB
  bf16x8* Df  = (bf16x8*)(ws + 262144);        // 32 KB
  float2* E   = (float2*)(ws + (1u << 20));    // 4.19 MB
  uint4*  P0  = (uint4*)(ws + (16u << 20));    // 16.8 MB packed bf16 partials

  k_prep<<<56, 256, 0, stream>>>(Bre, Bim, Cre, Cim, Dm, Bfr, Bfi, Cf, Df);
  k_chunkP<<<Bn * NC, 256, 0, stream>>>(u, lre, lim, Bfr, Bfi, Cf, Df, E, P0);
  k_scan<<<256, 256, 0, stream>>>(lre, lim, E);
  k_main2<<<Bn * NC, 256, 0, stream>>>(lre, lim, Cf, E, P0, out);
}